// Round 5
// baseline (134.356 us; speedup 1.0000x reference)
//
#include <hip/hip_runtime.h>
#include <math.h>

#define N 8192
#define D 256
#define QBLK 256          // 8 waves x 32 q-rows
#define KBLK 64

typedef float f32x4 __attribute__((ext_vector_type(4)));
typedef short bf16x8 __attribute__((ext_vector_type(8)));

#define MFMA(a, b, c) __builtin_amdgcn_mfma_f32_16x16x32_bf16((a), (b), (c), 0, 0, 0)
#define BAR() __builtin_amdgcn_s_barrier()

__device__ __forceinline__ unsigned short f2b(float f) {
    unsigned u = __builtin_bit_cast(unsigned, f);
    u = u + 0x7fffu + ((u >> 16) & 1u);            // RNE
    return (unsigned short)(u >> 16);
}
__device__ __forceinline__ unsigned pk2(float a, float b) {
    return (unsigned)f2b(a) | ((unsigned)f2b(b) << 16);
}
__device__ __forceinline__ unsigned cvtpk(float a, float b) {
    unsigned r;
    asm("v_cvt_pk_bf16_f32 %0, %1, %2" : "=v"(r) : "v"(a), "v"(b));
    return r;
}
__device__ __forceinline__ float b2f(short s) {
    unsigned x = ((unsigned)(unsigned short)s) << 16;
    return __builtin_bit_cast(float, x);
}

// ---------------------------------------------------------------------------
// QKV projection via MFMA (unchanged — verified). Q,K row-major bf16; V
// transposed (Vt[d][key]).
// ---------------------------------------------------------------------------
__global__ __launch_bounds__(256) void proj_mfma(
    const float* __restrict__ X, const float* __restrict__ Wq,
    const float* __restrict__ Wk, const float* __restrict__ Wv,
    unsigned short* __restrict__ Qb, unsigned short* __restrict__ Kb,
    unsigned short* __restrict__ Vt)
{
    __shared__ char Wl[32768];
    const int z = blockIdx.z;
    const float* W = (z == 0) ? Wq : (z == 1) ? Wk : Wv;
    const int r0 = blockIdx.x * 64;
    const int c0 = blockIdx.y * 64;
    const int t = threadIdx.x, w = t >> 6, l = t & 63;
    const int lo = l & 15, hi = l >> 4;

    #pragma unroll
    for (int i = 0; i < 16; ++i) {
        int e4 = t + i * 256;
        int col = e4 >> 6, kk4 = e4 & 63;
        float4 f = *(const float4*)&W[(size_t)(c0 + col) * D + kk4 * 4];
        unsigned long long v = (unsigned long long)pk2(f.x, f.y)
                             | ((unsigned long long)pk2(f.z, f.w) << 32);
        *(unsigned long long*)(Wl + col * 512 + ((kk4 * 8) ^ ((col & 7) << 4))) = v;
    }
    __syncthreads();

    bf16x8 xf[8];
    {
        const float* xr = X + (size_t)(r0 + w * 16 + lo) * D;
        #pragma unroll
        for (int ks = 0; ks < 8; ++ks) {
            float4 a = *(const float4*)(xr + ks * 32 + hi * 8);
            float4 b = *(const float4*)(xr + ks * 32 + hi * 8 + 4);
            bf16x8 v;
            v[0] = (short)f2b(a.x); v[1] = (short)f2b(a.y);
            v[2] = (short)f2b(a.z); v[3] = (short)f2b(a.w);
            v[4] = (short)f2b(b.x); v[5] = (short)f2b(b.y);
            v[6] = (short)f2b(b.z); v[7] = (short)f2b(b.w);
            xf[ks] = v;
        }
    }

    f32x4 acc[4];
    #pragma unroll
    for (int nc = 0; nc < 4; ++nc) acc[nc] = (f32x4){0.f, 0.f, 0.f, 0.f};
    #pragma unroll
    for (int ks = 0; ks < 8; ++ks) {
        #pragma unroll
        for (int nc = 0; nc < 4; ++nc) {
            int col = nc * 16 + lo;
            bf16x8 wf = *(const bf16x8*)(Wl + col * 512 +
                                         ((ks * 64 + hi * 16) ^ ((col & 7) << 4)));
            acc[nc] = MFMA(xf[ks], wf, acc[nc]);
        }
    }

    if (z < 2) {
        unsigned short* Y = z ? Kb : Qb;
        #pragma unroll
        for (int nc = 0; nc < 4; ++nc)
            #pragma unroll
            for (int r = 0; r < 4; ++r)
                Y[(size_t)(r0 + w * 16 + hi * 4 + r) * D + c0 + nc * 16 + lo] = f2b(acc[nc][r]);
    } else {
        #pragma unroll
        for (int nc = 0; nc < 4; ++nc) {
            unsigned long long v = (unsigned long long)pk2(acc[nc][0], acc[nc][1])
                                 | ((unsigned long long)pk2(acc[nc][2], acc[nc][3]) << 32);
            *(unsigned long long*)&Vt[(size_t)(c0 + nc * 16 + lo) * N + r0 + w * 16 + hi * 4] = v;
        }
    }
}

// ---------------------------------------------------------------------------
// Staging: K rows in permuted order pi so QK^T lane-ownership == PV A-frag
// layout (in-register P). 8 global_load_lds per thread per call.
// ---------------------------------------------------------------------------
__device__ __forceinline__ void stage_tile8(
    const unsigned short* __restrict__ Kb, const unsigned short* __restrict__ Vt,
    char* kbuf, char* vbuf, int kt, int t)
{
    #pragma unroll
    for (int i = 0; i < 4; ++i) {
        int c = t + i * 512;                       // 16B chunk id, 0..2047
        {
            int row = c >> 5, xc = c & 31;         // K: 64 rows x 32 chunks
            int pk = ((row >> 5) << 5) | (((row >> 2) & 3) << 3)
                   | (((row >> 4) & 1) << 2) | (row & 3);
            const unsigned short* gp = Kb + (size_t)(kt + pk) * D + (xc ^ (row & 7)) * 8;
            __builtin_amdgcn_global_load_lds(
                (const __attribute__((address_space(1))) void*)gp,
                (__attribute__((address_space(3))) void*)(kbuf + c * 16), 16, 0, 0);
        }
        {
            int dd = c >> 3, xc = c & 7;           // V: 256 rows x 8 chunks
            const unsigned short* gp = Vt + (size_t)dd * N + kt + (xc ^ (dd & 7)) * 8;
            __builtin_amdgcn_global_load_lds(
                (const __attribute__((address_space(1))) void*)gp,
                (__attribute__((address_space(3))) void*)(vbuf + c * 16), 16, 0, 0);
        }
    }
}

// ---------------------------------------------------------------------------
// Flash attention: 8 waves x 32 q-rows, KBLK=64, K-split across blocks.
// Counted-vmcnt pipeline (no vmcnt(0) drains mid-loop), base-2 softmax with
// full defer (cross-lane reduce only on rare rescale), per-lane partial l.
// LDS: K dbuf 2x32K @0, V dbuf 2x32K @65536 -> 131072 B.
// ---------------------------------------------------------------------------
template <int KSPLIT>
__global__ __launch_bounds__(512, 2) void attn_mfma(
    const unsigned short* __restrict__ Qb,
    const unsigned short* __restrict__ Kb,
    const unsigned short* __restrict__ Vt,
    unsigned short* __restrict__ Opart,
    float2* __restrict__ ml)
{
    extern __shared__ char smem[];
    const int t = threadIdx.x;
    const int w = t >> 6;
    const int l = t & 63;
    const int lo = l & 15;
    const int hi = l >> 4;
    const int q0 = blockIdx.x * QBLK + w * 32;
    const int split = blockIdx.y;
    const int kbase = split * (N / KSPLIT);
    const int NTS = N / KSPLIT / KBLK;

    bf16x8 qf[2][8];
    #pragma unroll
    for (int s = 0; s < 2; ++s) {
        const unsigned short* qrow = Qb + (size_t)(q0 + s * 16 + lo) * D;
        #pragma unroll
        for (int ks = 0; ks < 8; ++ks)
            qf[s][ks] = *(const bf16x8*)(qrow + ks * 32 + hi * 8);
    }

    // prologue: 2-deep prefetch
    stage_tile8(Kb, Vt, smem, smem + 65536, kbase, t);
    stage_tile8(Kb, Vt, smem + 32768, smem + 65536 + 32768, kbase + KBLK, t);

    f32x4 Oacc[2][16];
    #pragma unroll
    for (int s = 0; s < 2; ++s)
        #pragma unroll
        for (int i = 0; i < 16; ++i) Oacc[s][i] = (f32x4){0.f, 0.f, 0.f, 0.f};
    float m_run[2] = {-INFINITY, -INFINITY};
    float l_run[2] = {0.f, 0.f};
    const float scale2 = 0.09016994f;              // (1/16) * log2(e)

    asm volatile("s_waitcnt vmcnt(8)" ::: "memory");   // tile 0 landed
    BAR();

    for (int tt = 0; tt < NTS; ++tt) {
        const int cur = tt & 1;
        const char* Kl = smem + cur * 32768;
        const char* Vl = smem + 65536 + cur * 32768;

        // ---- S^T = K . Q^T (phys keys permuted by pi)
        f32x4 sacc[2][4];
        #pragma unroll
        for (int s = 0; s < 2; ++s)
            #pragma unroll
            for (int kg = 0; kg < 4; ++kg) sacc[s][kg] = (f32x4){0.f, 0.f, 0.f, 0.f};
        __builtin_amdgcn_s_setprio(1);
        #pragma unroll
        for (int ks = 0; ks < 8; ++ks) {
            #pragma unroll
            for (int kg = 0; kg < 4; ++kg) {
                int key = kg * 16 + lo;
                bf16x8 kf = *(const bf16x8*)(Kl + key * 512 +
                                             ((ks * 64 + hi * 16) ^ ((key & 7) << 4)));
                sacc[0][kg] = MFMA(kf, qf[0][ks], sacc[0][kg]);
                sacc[1][kg] = MFMA(kf, qf[1][ks], sacc[1][kg]);
            }
        }
        __builtin_amdgcn_s_setprio(0);

        // ---- per-lane tile max (base-2 domain)
        float mx[2];
        #pragma unroll
        for (int s = 0; s < 2; ++s) {
            float m = -INFINITY;
            #pragma unroll
            for (int kg = 0; kg < 4; ++kg)
                #pragma unroll
                for (int r = 0; r < 4; ++r) m = fmaxf(m, sacc[s][kg][r]);
            mx[s] = m * scale2;
        }

        // T13 full defer: cross-lane reduce + rescale only when a lane max
        // escapes the +11 (base-2) headroom. Rare after tile 0.
        bool need = (mx[0] > m_run[0] + 11.0f) || (mx[1] > m_run[1] + 11.0f);
        if (__builtin_expect(__any(need), 0)) {
            #pragma unroll
            for (int s = 0; s < 2; ++s) {
                float m = mx[s];
                m = fmaxf(m, __shfl_xor(m, 16));
                m = fmaxf(m, __shfl_xor(m, 32));
                float m_new = fmaxf(m_run[s], m);
                float corr = exp2f(m_run[s] - m_new);
                m_run[s] = m_new;
                l_run[s] *= corr;
                float cr0 = __shfl(corr, hi * 4 + 0);
                float cr1 = __shfl(corr, hi * 4 + 1);
                float cr2 = __shfl(corr, hi * 4 + 2);
                float cr3 = __shfl(corr, hi * 4 + 3);
                #pragma unroll
                for (int nc = 0; nc < 16; ++nc) {
                    Oacc[s][nc][0] *= cr0; Oacc[s][nc][1] *= cr1;
                    Oacc[s][nc][2] *= cr2; Oacc[s][nc][3] *= cr3;
                }
            }
        }

        // ---- P = 2^(S*scale2 - m); per-lane partial sums (reduce deferred)
        bf16x8 pa[2][2];
        float ts[2];
        #pragma unroll
        for (int s = 0; s < 2; ++s) {
            float p[16];
            float sum = 0.f;
            #pragma unroll
            for (int kg = 0; kg < 4; ++kg)
                #pragma unroll
                for (int r = 0; r < 4; ++r) {
                    float pv = exp2f(sacc[s][kg][r] * scale2 - m_run[s]);
                    p[kg * 4 + r] = pv;
                    sum += pv;
                }
            ts[s] = sum;
            union { unsigned u[4]; bf16x8 v; } u0, u1;
            #pragma unroll
            for (int j = 0; j < 4; ++j) {
                u0.u[j] = cvtpk(p[j * 2], p[j * 2 + 1]);
                u1.u[j] = cvtpk(p[8 + j * 2], p[8 + j * 2 + 1]);
            }
            pa[s][0] = u0.v;
            pa[s][1] = u1.v;
        }

        // ---- PV
        __builtin_amdgcn_s_setprio(1);
        #pragma unroll
        for (int nc = 0; nc < 16; ++nc) {
            int dd = nc * 16 + lo;
            bf16x8 v0 = *(const bf16x8*)(Vl + dd * 128 + ((hi * 16) ^ ((dd & 7) << 4)));
            bf16x8 v1 = *(const bf16x8*)(Vl + dd * 128 + ((64 + hi * 16) ^ ((dd & 7) << 4)));
            Oacc[0][nc] = MFMA(pa[0][0], v0, Oacc[0][nc]);
            Oacc[0][nc] = MFMA(pa[0][1], v1, Oacc[0][nc]);
            Oacc[1][nc] = MFMA(pa[1][0], v0, Oacc[1][nc]);
            Oacc[1][nc] = MFMA(pa[1][1], v1, Oacc[1][nc]);
        }
        __builtin_amdgcn_s_setprio(0);

        l_run[0] += ts[0];
        l_run[1] += ts[1];

        // ---- pipeline control: no vmcnt(0) drains mid-loop
        asm volatile("" ::: "memory");
        BAR();                                     // all waves done reading buf[cur]
        if (tt + 2 < NTS) {
            stage_tile8(Kb, Vt, smem + cur * 32768, smem + 65536 + cur * 32768,
                        kbase + (tt + 2) * KBLK, t);
            asm volatile("s_waitcnt vmcnt(8)" ::: "memory");   // tile t+1 landed
            BAR();
        } else if (tt + 1 < NTS) {
            asm volatile("s_waitcnt vmcnt(0)" ::: "memory");
            BAR();
        }
    }

    // ---- epilogue: reduce per-lane l partials, write O~ (bf16) + (m, l)
    #pragma unroll
    for (int s = 0; s < 2; ++s) {
        l_run[s] += __shfl_xor(l_run[s], 16);
        l_run[s] += __shfl_xor(l_run[s], 32);
    }
    #pragma unroll
    for (int s = 0; s < 2; ++s) {
        const int qrow = q0 + s * 16 + hi * 4;
        #pragma unroll
        for (int nc = 0; nc < 16; ++nc)
            #pragma unroll
            for (int r = 0; r < 4; ++r)
                Opart[((size_t)split * N + qrow + r) * D + nc * 16 + lo] = f2b(Oacc[s][nc][r]);
        if (hi == 0)
            ml[(size_t)split * N + q0 + s * 16 + lo] = make_float2(m_run[s], l_run[s]);
    }
}

// ---------------------------------------------------------------------------
// Combine (base-2 m): O = sum_i 2^(m_i-M) O~_i / sum_i 2^(m_i-M) l_i
// ---------------------------------------------------------------------------
__global__ __launch_bounds__(256) void combine_kernel(
    const unsigned short* __restrict__ Opart, const float2* __restrict__ ml,
    float* __restrict__ out, int nsplit)
{
    int idx = blockIdx.x * 256 + threadIdx.x;
    int q = idx >> 5;
    int d0 = (idx & 31) * 8;

    float M = -INFINITY;
    for (int i = 0; i < nsplit; ++i) M = fmaxf(M, ml[(size_t)i * N + q].x);
    float L = 0.f;
    float acc[8] = {};
    for (int i = 0; i < nsplit; ++i) {
        float2 v = ml[(size_t)i * N + q];
        float wgt = exp2f(v.x - M);
        L += wgt * v.y;
        bf16x8 ov = *(const bf16x8*)&Opart[((size_t)i * N + q) * D + d0];
        #pragma unroll
        for (int j = 0; j < 8; ++j) acc[j] += wgt * b2f(ov[j]);
    }
    float r = 1.f / L;
    #pragma unroll
    for (int j = 0; j < 8; ++j) out[(size_t)q * D + d0 + j] = acc[j] * r;
}

extern "C" void kernel_launch(void* const* d_in, const int* in_sizes, int n_in,
                              void* d_out, int out_size, void* d_ws, size_t ws_size,
                              hipStream_t stream) {
    const float* X  = (const float*)d_in[0];
    const float* Wq = (const float*)d_in[1];
    const float* Wk = (const float*)d_in[2];
    const float* Wv = (const float*)d_in[3];

    unsigned short* ws = (unsigned short*)d_ws;
    const size_t ndq = (size_t)N * D;
    unsigned short* Qb = ws;
    unsigned short* Kb = ws + ndq;
    unsigned short* Vt = ws + 2 * ndq;
    unsigned short* Opart = ws + 3 * ndq;

    auto need = [ndq](int ks) {
        return (size_t)(3 + ks) * ndq * 2 + (size_t)ks * N * 8;
    };
    const int ksplit = (ws_size >= need(8)) ? 8 : (ws_size >= need(4)) ? 4 : 2;
    float2* ml = (float2*)(ws + (3 + ksplit) * ndq);

    (void)hipFuncSetAttribute((const void*)attn_mfma<8>,
                              hipFuncAttributeMaxDynamicSharedMemorySize, 131072);
    (void)hipFuncSetAttribute((const void*)attn_mfma<4>,
                              hipFuncAttributeMaxDynamicSharedMemorySize, 131072);
    (void)hipFuncSetAttribute((const void*)attn_mfma<2>,
                              hipFuncAttributeMaxDynamicSharedMemorySize, 131072);

    proj_mfma<<<dim3(N / 64, D / 64, 3), 256, 0, stream>>>(X, Wq, Wk, Wv, Qb, Kb, Vt);
    if (ksplit == 8)
        attn_mfma<8><<<dim3(N / QBLK, 8), 512, 131072, stream>>>(Qb, Kb, Vt, Opart, ml);
    else if (ksplit == 4)
        attn_mfma<4><<<dim3(N / QBLK, 4), 512, 131072, stream>>>(Qb, Kb, Vt, Opart, ml);
    else
        attn_mfma<2><<<dim3(N / QBLK, 2), 512, 131072, stream>>>(Qb, Kb, Vt, Opart, ml);
    combine_kernel<<<(N * D / 8) / 256, 256, 0, stream>>>(Opart, ml, (float*)d_out, ksplit);
}

// Round 6
// 118.095 us; speedup vs baseline: 1.1377x; 1.1377x over previous
//
#include <hip/hip_runtime.h>
#include <math.h>

#define N 8192
#define D 256
#define QBLK 128          // 4 waves x 32 q-rows
#define KBLK 32

typedef float f32x4 __attribute__((ext_vector_type(4)));
typedef short bf16x8 __attribute__((ext_vector_type(8)));

#define MFMA(a, b, c) __builtin_amdgcn_mfma_f32_16x16x32_bf16((a), (b), (c), 0, 0, 0)
#define BAR() __builtin_amdgcn_s_barrier()

__device__ __forceinline__ unsigned short f2b(float f) {
    unsigned u = __builtin_bit_cast(unsigned, f);
    u = u + 0x7fffu + ((u >> 16) & 1u);            // RNE
    return (unsigned short)(u >> 16);
}
__device__ __forceinline__ unsigned pk2(float a, float b) {
    return (unsigned)f2b(a) | ((unsigned)f2b(b) << 16);
}
__device__ __forceinline__ unsigned cvtpk(float a, float b) {
    unsigned r;
    asm("v_cvt_pk_bf16_f32 %0, %1, %2" : "=v"(r) : "v"(a), "v"(b));
    return r;
}
__device__ __forceinline__ float b2f(short s) {
    unsigned x = ((unsigned)(unsigned short)s) << 16;
    return __builtin_bit_cast(float, x);
}

// ---------------------------------------------------------------------------
// QKV projection via MFMA (unchanged — verified). Q,K row-major bf16; V
// transposed (Vt[d][key]).
// ---------------------------------------------------------------------------
__global__ __launch_bounds__(256) void proj_mfma(
    const float* __restrict__ X, const float* __restrict__ Wq,
    const float* __restrict__ Wk, const float* __restrict__ Wv,
    unsigned short* __restrict__ Qb, unsigned short* __restrict__ Kb,
    unsigned short* __restrict__ Vt)
{
    __shared__ char Wl[32768];
    const int z = blockIdx.z;
    const float* W = (z == 0) ? Wq : (z == 1) ? Wk : Wv;
    const int r0 = blockIdx.x * 64;
    const int c0 = blockIdx.y * 64;
    const int t = threadIdx.x, w = t >> 6, l = t & 63;
    const int lo = l & 15, hi = l >> 4;

    #pragma unroll
    for (int i = 0; i < 16; ++i) {
        int e4 = t + i * 256;
        int col = e4 >> 6, kk4 = e4 & 63;
        float4 f = *(const float4*)&W[(size_t)(c0 + col) * D + kk4 * 4];
        unsigned long long v = (unsigned long long)pk2(f.x, f.y)
                             | ((unsigned long long)pk2(f.z, f.w) << 32);
        *(unsigned long long*)(Wl + col * 512 + ((kk4 * 8) ^ ((col & 7) << 4))) = v;
    }
    __syncthreads();

    bf16x8 xf[8];
    {
        const float* xr = X + (size_t)(r0 + w * 16 + lo) * D;
        #pragma unroll
        for (int ks = 0; ks < 8; ++ks) {
            float4 a = *(const float4*)(xr + ks * 32 + hi * 8);
            float4 b = *(const float4*)(xr + ks * 32 + hi * 8 + 4);
            bf16x8 v;
            v[0] = (short)f2b(a.x); v[1] = (short)f2b(a.y);
            v[2] = (short)f2b(a.z); v[3] = (short)f2b(a.w);
            v[4] = (short)f2b(b.x); v[5] = (short)f2b(b.y);
            v[6] = (short)f2b(b.z); v[7] = (short)f2b(b.w);
            xf[ks] = v;
        }
    }

    f32x4 acc[4];
    #pragma unroll
    for (int nc = 0; nc < 4; ++nc) acc[nc] = (f32x4){0.f, 0.f, 0.f, 0.f};
    #pragma unroll
    for (int ks = 0; ks < 8; ++ks) {
        #pragma unroll
        for (int nc = 0; nc < 4; ++nc) {
            int col = nc * 16 + lo;
            bf16x8 wf = *(const bf16x8*)(Wl + col * 512 +
                                         ((ks * 64 + hi * 16) ^ ((col & 7) << 4)));
            acc[nc] = MFMA(xf[ks], wf, acc[nc]);
        }
    }

    if (z < 2) {
        unsigned short* Y = z ? Kb : Qb;
        #pragma unroll
        for (int nc = 0; nc < 4; ++nc)
            #pragma unroll
            for (int r = 0; r < 4; ++r)
                Y[(size_t)(r0 + w * 16 + hi * 4 + r) * D + c0 + nc * 16 + lo] = f2b(acc[nc][r]);
    } else {
        #pragma unroll
        for (int nc = 0; nc < 4; ++nc) {
            unsigned long long v = (unsigned long long)pk2(acc[nc][0], acc[nc][1])
                                 | ((unsigned long long)pk2(acc[nc][2], acc[nc][3]) << 32);
            *(unsigned long long*)&Vt[(size_t)(c0 + nc * 16 + lo) * N + r0 + w * 16 + hi * 4] = v;
        }
    }
}

// ---------------------------------------------------------------------------
// Staging for 256-thread blocks, KBLK=32.
// K: 32 rows x 512 B, rows staged in permuted order pi (in-register P):
//    pi(row) = {b3b2 -> b4b3, b4 -> b2, b1b0}; swizzle ^(row&7) on 16B chunks.
// V: 256 rows x 64 B, linear (row parity spreads banks; no swizzle needed).
// 8 global_load_lds per thread per call (4 K + 4 V).
// ---------------------------------------------------------------------------
__device__ __forceinline__ void stage_tile4(
    const unsigned short* __restrict__ Kb, const unsigned short* __restrict__ Vt,
    char* kbuf, char* vbuf, int kt, int t)
{
    #pragma unroll
    for (int i = 0; i < 4; ++i) {
        int c = t + i * 256;                       // 16B chunk id, 0..1023
        {
            int row = c >> 5, xc = c & 31;         // K: 32 rows x 32 chunks
            int pk = (((row >> 2) & 3) << 3) | (((row >> 4) & 1) << 2) | (row & 3);
            const unsigned short* gp = Kb + (size_t)(kt + pk) * D + (xc ^ (row & 7)) * 8;
            __builtin_amdgcn_global_load_lds(
                (const __attribute__((address_space(1))) void*)gp,
                (__attribute__((address_space(3))) void*)(kbuf + c * 16), 16, 0, 0);
        }
        {
            int dd = c >> 2, xc = c & 3;           // V: 256 rows x 4 chunks
            const unsigned short* gp = Vt + (size_t)dd * N + kt + xc * 8;
            __builtin_amdgcn_global_load_lds(
                (const __attribute__((address_space(1))) void*)gp,
                (__attribute__((address_space(3))) void*)(vbuf + c * 16), 16, 0, 0);
        }
    }
}

// ---------------------------------------------------------------------------
// Flash attention: 4 waves x 32 q-rows (QBLK=128), KBLK=32, K-split across
// blocks. 64 KB LDS/block -> 2 independent blocks/CU (decoupled barriers).
// 1D grid; split = bid % KSPLIT puts each split on one XCD (L2 locality).
// LDS: K dbuf 2x16K @0, V dbuf 2x16K @32768 -> 65536 B.
// ---------------------------------------------------------------------------
template <int KSPLIT>
__global__ __launch_bounds__(256, 2) void attn_mfma(
    const unsigned short* __restrict__ Qb,
    const unsigned short* __restrict__ Kb,
    const unsigned short* __restrict__ Vt,
    unsigned short* __restrict__ Opart,
    float2* __restrict__ ml)
{
    extern __shared__ char smem[];
    const int t = threadIdx.x;
    const int w = t >> 6;
    const int l = t & 63;
    const int lo = l & 15;
    const int hi = l >> 4;
    const int bid = blockIdx.x;
    const int split = bid % KSPLIT;
    const int xblk = bid / KSPLIT;
    const int q0 = xblk * QBLK + w * 32;
    const int kbase = split * (N / KSPLIT);
    const int NTS = N / KSPLIT / KBLK;

    bf16x8 qf[2][8];
    #pragma unroll
    for (int s = 0; s < 2; ++s) {
        const unsigned short* qrow = Qb + (size_t)(q0 + s * 16 + lo) * D;
        #pragma unroll
        for (int ks = 0; ks < 8; ++ks)
            qf[s][ks] = *(const bf16x8*)(qrow + ks * 32 + hi * 8);
    }

    // prologue: 2-deep prefetch
    stage_tile4(Kb, Vt, smem, smem + 32768, kbase, t);
    stage_tile4(Kb, Vt, smem + 16384, smem + 32768 + 16384, kbase + KBLK, t);

    f32x4 Oacc[2][16];
    #pragma unroll
    for (int s = 0; s < 2; ++s)
        #pragma unroll
        for (int i = 0; i < 16; ++i) Oacc[s][i] = (f32x4){0.f, 0.f, 0.f, 0.f};
    float m_run[2] = {-INFINITY, -INFINITY};
    float l_run[2] = {0.f, 0.f};
    const float scale2 = 0.09016994f;              // (1/16) * log2(e)

    asm volatile("s_waitcnt vmcnt(8)" ::: "memory");   // tile 0 landed
    BAR();

    for (int tt = 0; tt < NTS; ++tt) {
        const int cur = tt & 1;
        const char* Kl = smem + cur * 16384;
        const char* Vl = smem + 32768 + cur * 16384;

        // ---- S^T = K . Q^T (phys keys permuted by pi)
        f32x4 sacc[2][2];
        #pragma unroll
        for (int s = 0; s < 2; ++s)
            #pragma unroll
            for (int kg = 0; kg < 2; ++kg) sacc[s][kg] = (f32x4){0.f, 0.f, 0.f, 0.f};
        __builtin_amdgcn_s_setprio(1);
        #pragma unroll
        for (int ks = 0; ks < 8; ++ks) {
            #pragma unroll
            for (int kg = 0; kg < 2; ++kg) {
                int key = kg * 16 + lo;
                bf16x8 kf = *(const bf16x8*)(Kl + key * 512 +
                                             ((ks * 64 + hi * 16) ^ ((key & 7) << 4)));
                sacc[0][kg] = MFMA(kf, qf[0][ks], sacc[0][kg]);
                sacc[1][kg] = MFMA(kf, qf[1][ks], sacc[1][kg]);
            }
        }
        __builtin_amdgcn_s_setprio(0);

        // ---- per-lane tile max (base-2 domain)
        float mx[2];
        #pragma unroll
        for (int s = 0; s < 2; ++s) {
            float m = -INFINITY;
            #pragma unroll
            for (int kg = 0; kg < 2; ++kg)
                #pragma unroll
                for (int r = 0; r < 4; ++r) m = fmaxf(m, sacc[s][kg][r]);
            mx[s] = m * scale2;
        }

        // T13 full defer: cross-lane reduce + rescale only on rare overflow
        bool need = (mx[0] > m_run[0] + 11.0f) || (mx[1] > m_run[1] + 11.0f);
        if (__builtin_expect(__any(need), 0)) {
            #pragma unroll
            for (int s = 0; s < 2; ++s) {
                float m = mx[s];
                m = fmaxf(m, __shfl_xor(m, 16));
                m = fmaxf(m, __shfl_xor(m, 32));
                float m_new = fmaxf(m_run[s], m);
                float corr = exp2f(m_run[s] - m_new);
                m_run[s] = m_new;
                l_run[s] *= corr;
                float cr0 = __shfl(corr, hi * 4 + 0);
                float cr1 = __shfl(corr, hi * 4 + 1);
                float cr2 = __shfl(corr, hi * 4 + 2);
                float cr3 = __shfl(corr, hi * 4 + 3);
                #pragma unroll
                for (int nc = 0; nc < 16; ++nc) {
                    Oacc[s][nc][0] *= cr0; Oacc[s][nc][1] *= cr1;
                    Oacc[s][nc][2] *= cr2; Oacc[s][nc][3] *= cr3;
                }
            }
        }

        // ---- P = 2^(S*scale2 - m); pack in-register (key order matches V)
        bf16x8 pa[2];
        float ts[2];
        #pragma unroll
        for (int s = 0; s < 2; ++s) {
            float p[8];
            float sum = 0.f;
            #pragma unroll
            for (int kg = 0; kg < 2; ++kg)
                #pragma unroll
                for (int r = 0; r < 4; ++r) {
                    float pv = exp2f(sacc[s][kg][r] * scale2 - m_run[s]);
                    p[kg * 4 + r] = pv;
                    sum += pv;
                }
            ts[s] = sum;
            union { unsigned u[4]; bf16x8 v; } u0;
            #pragma unroll
            for (int j = 0; j < 4; ++j)
                u0.u[j] = cvtpk(p[j * 2], p[j * 2 + 1]);
            pa[s] = u0.v;
        }

        // ---- PV
        __builtin_amdgcn_s_setprio(1);
        #pragma unroll
        for (int nc = 0; nc < 16; ++nc) {
            int dd = nc * 16 + lo;
            bf16x8 v0 = *(const bf16x8*)(Vl + dd * 64 + hi * 16);
            Oacc[0][nc] = MFMA(pa[0], v0, Oacc[0][nc]);
            Oacc[1][nc] = MFMA(pa[1], v0, Oacc[1][nc]);
        }
        __builtin_amdgcn_s_setprio(0);

        l_run[0] += ts[0];
        l_run[1] += ts[1];

        // ---- pipeline control: no vmcnt(0) drains mid-loop
        asm volatile("" ::: "memory");
        BAR();                                     // all waves done reading buf[cur]
        if (tt + 2 < NTS) {
            stage_tile4(Kb, Vt, smem + cur * 16384, smem + 32768 + cur * 16384,
                        kbase + (tt + 2) * KBLK, t);
            asm volatile("s_waitcnt vmcnt(8)" ::: "memory");   // tile t+1 landed
            BAR();
        } else if (tt + 1 < NTS) {
            asm volatile("s_waitcnt vmcnt(0)" ::: "memory");
            BAR();
        }
    }

    // ---- epilogue: reduce per-lane l partials, write O~ (bf16) + (m, l)
    #pragma unroll
    for (int s = 0; s < 2; ++s) {
        l_run[s] += __shfl_xor(l_run[s], 16);
        l_run[s] += __shfl_xor(l_run[s], 32);
    }
    #pragma unroll
    for (int s = 0; s < 2; ++s) {
        const int qrow = q0 + s * 16 + hi * 4;
        #pragma unroll
        for (int nc = 0; nc < 16; ++nc)
            #pragma unroll
            for (int r = 0; r < 4; ++r)
                Opart[((size_t)split * N + qrow + r) * D + nc * 16 + lo] = f2b(Oacc[s][nc][r]);
        if (hi == 0)
            ml[(size_t)split * N + q0 + s * 16 + lo] = make_float2(m_run[s], l_run[s]);
    }
}

// ---------------------------------------------------------------------------
// Combine (base-2 m): O = sum_i 2^(m_i-M) O~_i / sum_i 2^(m_i-M) l_i
// ---------------------------------------------------------------------------
__global__ __launch_bounds__(256) void combine_kernel(
    const unsigned short* __restrict__ Opart, const float2* __restrict__ ml,
    float* __restrict__ out, int nsplit)
{
    int idx = blockIdx.x * 256 + threadIdx.x;
    int q = idx >> 5;
    int d0 = (idx & 31) * 8;

    float M = -INFINITY;
    for (int i = 0; i < nsplit; ++i) M = fmaxf(M, ml[(size_t)i * N + q].x);
    float L = 0.f;
    float acc[8] = {};
    for (int i = 0; i < nsplit; ++i) {
        float2 v = ml[(size_t)i * N + q];
        float wgt = exp2f(v.x - M);
        L += wgt * v.y;
        bf16x8 ov = *(const bf16x8*)&Opart[((size_t)i * N + q) * D + d0];
        #pragma unroll
        for (int j = 0; j < 8; ++j) acc[j] += wgt * b2f(ov[j]);
    }
    float r = 1.f / L;
    #pragma unroll
    for (int j = 0; j < 8; ++j) out[(size_t)q * D + d0 + j] = acc[j] * r;
}

extern "C" void kernel_launch(void* const* d_in, const int* in_sizes, int n_in,
                              void* d_out, int out_size, void* d_ws, size_t ws_size,
                              hipStream_t stream) {
    const float* X  = (const float*)d_in[0];
    const float* Wq = (const float*)d_in[1];
    const float* Wk = (const float*)d_in[2];
    const float* Wv = (const float*)d_in[3];

    unsigned short* ws = (unsigned short*)d_ws;
    const size_t ndq = (size_t)N * D;
    unsigned short* Qb = ws;
    unsigned short* Kb = ws + ndq;
    unsigned short* Vt = ws + 2 * ndq;
    unsigned short* Opart = ws + 3 * ndq;

    auto need = [ndq](int ks) {
        return (size_t)(3 + ks) * ndq * 2 + (size_t)ks * N * 8;
    };
    const int ksplit = (ws_size >= need(8)) ? 8 : (ws_size >= need(4)) ? 4 : 2;
    float2* ml = (float2*)(ws + (3 + ksplit) * ndq);

    (void)hipFuncSetAttribute((const void*)attn_mfma<8>,
                              hipFuncAttributeMaxDynamicSharedMemorySize, 65536);
    (void)hipFuncSetAttribute((const void*)attn_mfma<4>,
                              hipFuncAttributeMaxDynamicSharedMemorySize, 65536);
    (void)hipFuncSetAttribute((const void*)attn_mfma<2>,
                              hipFuncAttributeMaxDynamicSharedMemorySize, 65536);

    proj_mfma<<<dim3(N / 64, D / 64, 3), 256, 0, stream>>>(X, Wq, Wk, Wv, Qb, Kb, Vt);
    if (ksplit == 8)
        attn_mfma<8><<<dim3((N / QBLK) * 8), 256, 65536, stream>>>(Qb, Kb, Vt, Opart, ml);
    else if (ksplit == 4)
        attn_mfma<4><<<dim3((N / QBLK) * 4), 256, 65536, stream>>>(Qb, Kb, Vt, Opart, ml);
    else
        attn_mfma<2><<<dim3((N / QBLK) * 2), 256, 65536, stream>>>(Qb, Kb, Vt, Opart, ml);
    combine_kernel<<<(N * D / 8) / 256, 256, 0, stream>>>(Opart, ml, (float*)d_out, ksplit);
}